// Round 8
// baseline (524.801 us; speedup 1.0000x reference)
//
#include <hip/hip_runtime.h>
#include <hip/hip_bf16.h>
#include <math.h>

#define Gn 16000
#define Bn 4096
#define Ln 64
#define Sn 20000

typedef __attribute__((ext_vector_type(8))) short bf16x8;   // 8 bf16 = 4 VGPRs
typedef __attribute__((ext_vector_type(4))) float f32x4;    // MFMA C/D

#define LN2  0.6931471805599453f
#define RLN2 1.4426950408889634f

// ---------- device math helpers ----------

__device__ __forceinline__ float softplus_precise(float z) {
    return fmaxf(z, 0.0f) + log1pf(__expf(-fabsf(z)));
}

// accurate lgamma for z>0 (shift-8 Stirling), used only for the 100-entry table
__device__ __forceinline__ float lgamma_pos8(float z) {
    float p = z * (z + 1.f) * (z + 2.f) * (z + 3.f)
                * (z + 4.f) * (z + 5.f) * (z + 6.f) * (z + 7.f);
    float w = z + 8.f;
    return (w - 0.5f) * __logf(w) - w + 0.9189385332046727f
           + __fdividef(1.0f, 12.0f * w) - __logf(p);
}

__device__ __forceinline__ unsigned short f2bf(float f) {
    union { float f; unsigned int u; } v; v.f = f;
    unsigned int r = v.u + 0x7fff + ((v.u >> 16) & 1);   // RNE
    return (unsigned short)(r >> 16);
}

// ---------- precompute kernels ----------
//
// GENE PERMUTATION (as r7): within each 64-gene block, gene j = ln*4 + nb is
// stored at MFMA column c = (j&3)*16 + (j>>2), so each lane's 4 output
// columns are 4 consecutive genes -> x/lsp1c load as dwordx4.
// lsp1c[g] = (log_sigmoid(px_o[g]) - 1) / ln2   (log2 units for main)

__global__ void prep_genes(const float* __restrict__ W,
                           const float* __restrict__ px_o,
                           const float* __restrict__ eta,
                           const float* __restrict__ beta,
                           unsigned short* __restrict__ rhB,
                           float* __restrict__ lsp1c,
                           float* __restrict__ eps) {
    int idx = blockIdx.x * 256 + threadIdx.x;   // Gn*64 total, exact
    int g = idx >> 6, l = idx & 63;
    int j = g & 63, gb = g & ~63;
    int c = (j & 3) * 16 + (j >> 2);            // permuted MFMA column
    float bsp = softplus_precise(beta[g]);
    rhB[(size_t)(gb + c) * 64 + l] = f2bf(bsp * softplus_precise(W[idx]));
    if (idx < Gn) {
        eps[idx] = softplus_precise(eta[idx]);
        float o = px_o[idx];
        lsp1c[idx] = (-softplus_precise(-o) - 1.0f) * RLN2;
    }
}

__global__ void prep_spots(const float* __restrict__ V,
                           const int* __restrict__ ind_x,
                           unsigned short* __restrict__ vBg,
                           float* __restrict__ v64) {
    int idx = blockIdx.x * 256 + threadIdx.x;   // Bn*64 total, exact
    int b = idx >> 6, l = idx & 63;
    int s = ind_x[b];
    vBg[idx] = f2bf(softplus_precise(V[l * Sn + s]));
    if (idx < Bn) {
        int s2 = ind_x[idx];
        v64[idx] = softplus_precise(V[Ln * Sn + s2]);
    }
}

// u[l] = sum_g lsn[g]*rhat[g,l] (l<64);  u[64] = sum_g lsn[g]*eps[g]
// (fp32-exact; lets main drop the rr*lsn fma per element)
__global__ void prep_u(const float* __restrict__ W,
                       const float* __restrict__ px_o,
                       const float* __restrict__ eta,
                       const float* __restrict__ beta,
                       float* __restrict__ u) {
    const int l = blockIdx.x;   // 0..64
    float ss = 0.f;
    for (int g = threadIdx.x; g < Gn; g += 256) {
        float lsn = -softplus_precise(px_o[g]);
        float val = (l == 64) ? softplus_precise(eta[g])
                              : softplus_precise(beta[g]) * softplus_precise(W[g * 64 + l]);
        ss += lsn * val;
    }
    #pragma unroll
    for (int off = 32; off; off >>= 1) ss += __shfl_xor(ss, off, 64);
    __shared__ float red[4];
    if ((threadIdx.x & 63) == 0) red[threadIdx.x >> 6] = ss;
    __syncthreads();
    if (threadIdx.x == 0) u[l] = red[0] + red[1] + red[2] + red[3];
}

// out[b] = -sum_g rr[b,g]*lsn[g] = -dot(u, softplus(V[:, ind_x[b]]))  (exact fp32)
__global__ void spot_corr(const float* __restrict__ V,
                          const int* __restrict__ ind_x,
                          const float* __restrict__ u,
                          float* __restrict__ out) {
    int b = blockIdx.x * 256 + threadIdx.x;   // 4096 exact
    int s = ind_x[b];
    float c = 0.f;
    #pragma unroll 5
    for (int l = 0; l < 65; l++)
        c = fmaf(u[l], softplus_precise(V[l * Sn + s]), c);
    out[b] = -c;   // plain store: runs before main (stream-ordered)
}

// prior: parallel, atomicAdd into out[Bn+1] (out pre-zeroed by memset)
__global__ void prior_kernel(const float* __restrict__ eta, float* __restrict__ out) {
    int idx = blockIdx.x * 256 + threadIdx.x;
    float s = 0.f;
    if (idx < Gn) {
        float e = eta[idx];
        s = 0.9189385332046727f + 0.5f * e * e;
    }
    #pragma unroll
    for (int off = 32; off; off >>= 1) s += __shfl_xor(s, off, 64);
    __shared__ float red[4];
    if ((threadIdx.x & 63) == 0) red[threadIdx.x >> 6] = s;
    __syncthreads();
    if (threadIdx.x == 0) atomicAdd(&out[Bn + 1], red[0] + red[1] + red[2] + red[3]);
}

// ---------- main kernel: barrier-free, batched-ILP epilogue in log2 units ----------
//
// t2 = (s-0.5)log2 s - (rr-0.5)log2 rr + x*lsp1c - lfact2[x]
// contribution to out = -ln2 * sum(t2)     (rr*lsn handled by spot_corr)

__global__ __launch_bounds__(256, 4) void main_kernel(
    const int*            __restrict__ x,
    const unsigned short* __restrict__ rhB,
    const unsigned short* __restrict__ vBg,
    const float*          __restrict__ v64,
    const float*          __restrict__ lsp1cg,
    const float*          __restrict__ epsg,
    float*                __restrict__ out) {
    __shared__ float lfact2[100];   // lgamma(x+1)/ln2

    const int tid = threadIdx.x;
    if (tid < 100) lfact2[tid] = lgamma_pos8((float)tid + 1.0f) * RLN2;
    __syncthreads();

    const int g0 = blockIdx.x * 64;
    const int b0 = blockIdx.y * 64;
    const int wave = tid >> 6, lane = tid & 63;
    const int quad = lane >> 4, ln = lane & 15;
    const int mrow  = wave * 16 + ln;              // A-fragment m index
    const int brow0 = b0 + wave * 16 + quad * 4;   // C rows for this lane

    // x tile: 4 aligned int4 loads (lane's 4 genes consecutive: g0+ln*4..+3)
    int4 xq[4];
    #pragma unroll
    for (int r = 0; r < 4; r++)
        xq[r] = *(const int4*)(x + (size_t)(brow0 + r) * Gn + g0 + ln * 4);

    const float4 lsp1q = *(const float4*)(lsp1cg + g0 + ln * 4);
    const float4 epsq  = *(const float4*)(epsg   + g0 + ln * 4);
    const float4 vq    = *(const float4*)(v64 + brow0);

    // A fragments: vBg row (b0+mrow), 16B slices
    const unsigned short* aPtr = vBg + (size_t)(b0 + mrow) * 64 + quad * 8;
    bf16x8 af0 = *(const bf16x8*)(aPtr);
    bf16x8 af1 = *(const bf16x8*)(aPtr + 32);

    // B fragments: permuted rhB rows
    const unsigned short* bPtr = rhB + (size_t)(g0 + ln) * 64 + quad * 8;
    bf16x8 bf_[4][2];
    #pragma unroll
    for (int nb = 0; nb < 4; nb++) {
        bf_[nb][0] = *(const bf16x8*)(bPtr + nb * 1024);
        bf_[nb][1] = *(const bf16x8*)(bPtr + nb * 1024 + 32);
    }

    f32x4 acc[4];
    #pragma unroll
    for (int nb = 0; nb < 4; nb++) acc[nb] = (f32x4){0.f, 0.f, 0.f, 0.f};
    #pragma unroll
    for (int nb = 0; nb < 4; nb++) {
        acc[nb] = __builtin_amdgcn_mfma_f32_16x16x32_bf16(af0, bf_[nb][0], acc[nb], 0, 0, 0);
        acc[nb] = __builtin_amdgcn_mfma_f32_16x16x32_bf16(af1, bf_[nb][1], acc[nb], 0, 0, 0);
    }

    const float vvr[4]   = {vq.x, vq.y, vq.z, vq.w};
    const float lsp1v[4] = {lsp1q.x, lsp1q.y, lsp1q.z, lsp1q.w};
    const float ev4[4]   = {epsq.x, epsq.y, epsq.z, epsq.w};

    float rowpart[4] = {0.f, 0.f, 0.f, 0.f};
    // batched epilogue: 8 elements per phase -> 16 independent logs in flight
    #pragma unroll
    for (int h = 0; h < 2; h++) {
        float rr8[8], s8[8];
        #pragma unroll
        for (int jj = 0; jj < 8; jj++) {
            const int nb = h * 2 + (jj >> 2), r = jj & 3;
            const float rr = fmaf(ev4[nb], vvr[r], acc[nb][r]);
            rr8[jj] = rr;
            s8[jj]  = rr + (float)(((const int*)&xq[r])[nb]);
        }
        float ls8[8], lr8[8];
        #pragma unroll
        for (int jj = 0; jj < 8; jj++) {
            ls8[jj] = __log2f(s8[jj]);
            lr8[jj] = __log2f(rr8[jj]);
        }
        #pragma unroll
        for (int jj = 0; jj < 8; jj++) {
            const int nb = h * 2 + (jj >> 2), r = jj & 3;
            const int   xi = ((const int*)&xq[r])[nb];
            const float xf = (float)xi;
            float t = fmaf(xf, lsp1v[nb], -lfact2[xi]);
            t = fmaf(0.5f - rr8[jj], lr8[jj], t);
            t = fmaf(s8[jj] - 0.5f, ls8[jj], t);
            rowpart[r] += t;
        }
    }

    // reduce over the 16 gene-lanes of each quad, one atomic per row
    #pragma unroll
    for (int r = 0; r < 4; r++) {
        float v = rowpart[r];
        v += __shfl_xor(v, 1, 64);
        v += __shfl_xor(v, 2, 64);
        v += __shfl_xor(v, 4, 64);
        v += __shfl_xor(v, 8, 64);
        if (ln == 0) atomicAdd(&out[brow0 + r], -LN2 * v);
    }
}

// ---------- launch ----------

extern "C" void kernel_launch(void* const* d_in, const int* in_sizes, int n_in,
                              void* d_out, int out_size, void* d_ws, size_t ws_size,
                              hipStream_t stream) {
    const int*   x     = (const int*)d_in[0];
    const int*   ind_x = (const int*)d_in[2];
    const float* W     = (const float*)d_in[3];
    const float* px_o  = (const float*)d_in[4];
    const float* eta   = (const float*)d_in[5];
    const float* V     = (const float*)d_in[6];
    const float* beta  = (const float*)d_in[7];
    float* out = (float*)d_out;

    // ws layout (bytes):
    char* wsb = (char*)d_ws;
    unsigned short* rhB   = (unsigned short*)(wsb);                   // Gn*64*2 = 2,048,000
    unsigned short* vBg   = (unsigned short*)(wsb + 2048000);         // Bn*64*2 =   524,288
    float*          v64   = (float*)(wsb + 2572288);                  // Bn*4    =    16,384
    float*          lsp1c = (float*)(wsb + 2588672);                  // Gn*4
    float*          eps   = (float*)(wsb + 2652672);                  // Gn*4
    float*          u     = (float*)(wsb + 2716672);                  // 65*4

    // zero loss accumulators AND the two scalar slots
    hipMemsetAsync(d_out, 0, (Bn + 2) * sizeof(float), stream);

    prep_genes<<<(Gn * 64) / 256, 256, 0, stream>>>(W, px_o, eta, beta, rhB, lsp1c, eps);
    prep_spots<<<(Bn * 64) / 256, 256, 0, stream>>>(V, ind_x, vBg, v64);
    prep_u<<<65, 256, 0, stream>>>(W, px_o, eta, beta, u);
    spot_corr<<<Bn / 256, 256, 0, stream>>>(V, ind_x, u, out);
    prior_kernel<<<(Gn + 255) / 256, 256, 0, stream>>>(eta, out);

    dim3 grid(Gn / 64, Bn / 64);   // 250 x 64
    main_kernel<<<grid, 256, 0, stream>>>(x, rhB, vBg, v64, lsp1c, eps, out);
}

// Round 9
// 436.053 us; speedup vs baseline: 1.2035x; 1.2035x over previous
//
#include <hip/hip_runtime.h>
#include <hip/hip_bf16.h>
#include <math.h>

#define Gn 16000
#define Bn 4096
#define Ln 64
#define Sn 20000

typedef __attribute__((ext_vector_type(8))) short bf16x8;   // 8 bf16 = 4 VGPRs
typedef __attribute__((ext_vector_type(4))) float f32x4;    // MFMA C/D

#define LN2  0.6931471805599453f
#define RLN2 1.4426950408889634f

// ---------- device math helpers ----------

__device__ __forceinline__ float softplus_precise(float z) {
    return fmaxf(z, 0.0f) + log1pf(__expf(-fabsf(z)));
}

// raw v_log_f32 = log2(x); args here are always normal (>= ~5), so the
// libm denorm pre-scale/fixup (~5 instrs) is pure overhead we skip.
__device__ __forceinline__ float raw_log2(float v) {
    float r;
    asm("v_log_f32 %0, %1" : "=v"(r) : "v"(v));
    return r;
}

// accurate lgamma for z>0 (shift-8 Stirling), used only for the 100-entry table
__device__ __forceinline__ float lgamma_pos8(float z) {
    float p = z * (z + 1.f) * (z + 2.f) * (z + 3.f)
                * (z + 4.f) * (z + 5.f) * (z + 6.f) * (z + 7.f);
    float w = z + 8.f;
    return (w - 0.5f) * __logf(w) - w + 0.9189385332046727f
           + __fdividef(1.0f, 12.0f * w) - __logf(p);
}

__device__ __forceinline__ unsigned short f2bf(float f) {
    union { float f; unsigned int u; } v; v.f = f;
    unsigned int r = v.u + 0x7fff + ((v.u >> 16) & 1);   // RNE
    return (unsigned short)(r >> 16);
}

// ---------- precompute kernels ----------
//
// GENE PERMUTATION (as r7): within each 64-gene block, gene j = ln*4 + nb is
// stored at MFMA column c = (j&3)*16 + (j>>2), so each lane's 4 output
// columns are 4 consecutive genes -> x/consts load as dwordx4.
// lsp1c[g] = (log_sigmoid(px_o[g]) - 1)/ln2 ; lsn2[g] = log_sigmoid(-px_o[g])/ln2

__global__ void prep_genes(const float* __restrict__ W,
                           const float* __restrict__ px_o,
                           const float* __restrict__ eta,
                           const float* __restrict__ beta,
                           unsigned short* __restrict__ rhB,
                           float* __restrict__ lsp1c,
                           float* __restrict__ lsn2,
                           float* __restrict__ eps) {
    int idx = blockIdx.x * 256 + threadIdx.x;   // Gn*64 total, exact
    int g = idx >> 6, l = idx & 63;
    int j = g & 63, gb = g & ~63;
    int c = (j & 3) * 16 + (j >> 2);            // permuted MFMA column
    float bsp = softplus_precise(beta[g]);
    rhB[(size_t)(gb + c) * 64 + l] = f2bf(bsp * softplus_precise(W[idx]));
    if (idx < Gn) {
        eps[idx] = softplus_precise(eta[idx]);
        float o = px_o[idx];
        lsp1c[idx] = (-softplus_precise(-o) - 1.0f) * RLN2;
        lsn2[idx]  = -softplus_precise(o) * RLN2;
    }
}

__global__ void prep_spots(const float* __restrict__ V,
                           const int* __restrict__ ind_x,
                           unsigned short* __restrict__ vBg,
                           float* __restrict__ v64) {
    int idx = blockIdx.x * 256 + threadIdx.x;   // Bn*64 total, exact
    int b = idx >> 6, l = idx & 63;
    int s = ind_x[b];
    vBg[idx] = f2bf(softplus_precise(V[l * Sn + s]));
    if (idx < Bn) {
        int s2 = ind_x[idx];
        v64[idx] = softplus_precise(V[Ln * Sn + s2]);
    }
}

// prior: parallel, atomicAdd into out[Bn+1] (out pre-zeroed by memset)
__global__ void prior_kernel(const float* __restrict__ eta, float* __restrict__ out) {
    int idx = blockIdx.x * 256 + threadIdx.x;
    float s = 0.f;
    if (idx < Gn) {
        float e = eta[idx];
        s = 0.9189385332046727f + 0.5f * e * e;
    }
    #pragma unroll
    for (int off = 32; off; off >>= 1) s += __shfl_xor(s, off, 64);
    __shared__ float red[4];
    if ((threadIdx.x & 63) == 0) red[threadIdx.x >> 6] = s;
    __syncthreads();
    if (threadIdx.x == 0) atomicAdd(&out[Bn + 1], red[0] + red[1] + red[2] + red[3]);
}

// ---------- main kernel: 2 b-tiles per block, raw-log2 epilogue ----------
//
// t2 = (s-0.5)log2 s - (rr-0.5)log2 rr + x*lsp1c + rr*lsn2 - lfact2[x]
// out[b] += -ln2 * sum_g t2

__global__ __launch_bounds__(256) void main_kernel(
    const int*            __restrict__ x,
    const unsigned short* __restrict__ rhB,
    const unsigned short* __restrict__ vBg,
    const float*          __restrict__ v64,
    const float*          __restrict__ lsp1cg,
    const float*          __restrict__ lsn2g,
    const float*          __restrict__ epsg,
    float*                __restrict__ out) {
    __shared__ float lfact2[100];   // lgamma(x+1)/ln2

    const int tid = threadIdx.x;
    if (tid < 100) lfact2[tid] = lgamma_pos8((float)tid + 1.0f) * RLN2;
    __syncthreads();   // no VMEM in flight yet

    const int g0 = blockIdx.x * 64;
    const int b0 = blockIdx.y * 128;               // two 64-row tiles
    const int wave = tid >> 6, lane = tid & 63;
    const int quad = lane >> 4, ln = lane & 15;
    const int mrow = wave * 16 + ln;               // A-fragment m index
    const int rbase = wave * 16 + quad * 4;        // C row base within a tile

    // ---- issue ALL loads up front (deep MLP; tile1 latency hides under
    //      tile0 epilogue) ----

    // x: 8 aligned int4 (2 tiles x 4 rows); lane's genes g0+ln*4..+3
    int4 xq[2][4];
    #pragma unroll
    for (int t = 0; t < 2; t++)
        #pragma unroll
        for (int r = 0; r < 4; r++)
            xq[t][r] = *(const int4*)(x + (size_t)(b0 + t * 64 + rbase + r) * Gn + g0 + ln * 4);

    // per-gene constants (shared across tiles) + v64 rows per tile
    const float4 lsp1q = *(const float4*)(lsp1cg + g0 + ln * 4);
    const float4 lsn2q = *(const float4*)(lsn2g  + g0 + ln * 4);
    const float4 epsq  = *(const float4*)(epsg   + g0 + ln * 4);
    float4 vqt[2];
    #pragma unroll
    for (int t = 0; t < 2; t++)
        vqt[t] = *(const float4*)(v64 + b0 + t * 64 + rbase);

    // A fragments per tile; B fragments shared
    bf16x8 af[2][2];
    #pragma unroll
    for (int t = 0; t < 2; t++) {
        const unsigned short* aPtr = vBg + (size_t)(b0 + t * 64 + mrow) * 64 + quad * 8;
        af[t][0] = *(const bf16x8*)(aPtr);
        af[t][1] = *(const bf16x8*)(aPtr + 32);
    }
    const unsigned short* bPtr = rhB + (size_t)(g0 + ln) * 64 + quad * 8;
    bf16x8 bf_[4][2];
    #pragma unroll
    for (int nb = 0; nb < 4; nb++) {
        bf_[nb][0] = *(const bf16x8*)(bPtr + nb * 1024);
        bf_[nb][1] = *(const bf16x8*)(bPtr + nb * 1024 + 32);
    }

    // ---- MFMAs for both tiles ----
    f32x4 acc[2][4];
    #pragma unroll
    for (int t = 0; t < 2; t++)
        #pragma unroll
        for (int nb = 0; nb < 4; nb++) acc[t][nb] = (f32x4){0.f, 0.f, 0.f, 0.f};
    #pragma unroll
    for (int t = 0; t < 2; t++)
        #pragma unroll
        for (int nb = 0; nb < 4; nb++) {
            acc[t][nb] = __builtin_amdgcn_mfma_f32_16x16x32_bf16(af[t][0], bf_[nb][0], acc[t][nb], 0, 0, 0);
            acc[t][nb] = __builtin_amdgcn_mfma_f32_16x16x32_bf16(af[t][1], bf_[nb][1], acc[t][nb], 0, 0, 0);
        }

    const float lsp1v[4] = {lsp1q.x, lsp1q.y, lsp1q.z, lsp1q.w};
    const float lsn2v[4] = {lsn2q.x, lsn2q.y, lsn2q.z, lsn2q.w};
    const float ev4[4]   = {epsq.x, epsq.y, epsq.z, epsq.w};

    // ---- epilogues ----
    #pragma unroll
    for (int t = 0; t < 2; t++) {
        const float vvr[4] = {vqt[t].x, vqt[t].y, vqt[t].z, vqt[t].w};
        float rowpart[4] = {0.f, 0.f, 0.f, 0.f};
        #pragma unroll
        for (int nb = 0; nb < 4; nb++) {
            #pragma unroll
            for (int r = 0; r < 4; r++) {
                // acc[t][nb][r] = column nb*16+ln = gene g0+ln*4+nb (permuted B)
                const float rr = fmaf(ev4[nb], vvr[r], acc[t][nb][r]);
                const int   xi = ((const int*)&xq[t][r])[nb];
                const float xf = (float)xi;
                const float s  = rr + xf;
                const float ls = raw_log2(s);
                const float lr = raw_log2(rr);
                float u = fmaf(xf, lsp1v[nb], -lfact2[xi]);
                u = fmaf(rr, lsn2v[nb], u);
                u = fmaf(0.5f - rr, lr, u);
                u = fmaf(s - 0.5f, ls, u);
                rowpart[r] += u;
            }
        }
        #pragma unroll
        for (int r = 0; r < 4; r++) {
            float v = rowpart[r];
            v += __shfl_xor(v, 1, 64);
            v += __shfl_xor(v, 2, 64);
            v += __shfl_xor(v, 4, 64);
            v += __shfl_xor(v, 8, 64);
            if (ln == 0) atomicAdd(&out[b0 + t * 64 + rbase + r], -LN2 * v);
        }
    }
}

// ---------- launch ----------

extern "C" void kernel_launch(void* const* d_in, const int* in_sizes, int n_in,
                              void* d_out, int out_size, void* d_ws, size_t ws_size,
                              hipStream_t stream) {
    const int*   x     = (const int*)d_in[0];
    const int*   ind_x = (const int*)d_in[2];
    const float* W     = (const float*)d_in[3];
    const float* px_o  = (const float*)d_in[4];
    const float* eta   = (const float*)d_in[5];
    const float* V     = (const float*)d_in[6];
    const float* beta  = (const float*)d_in[7];
    float* out = (float*)d_out;

    // ws layout (bytes):
    char* wsb = (char*)d_ws;
    unsigned short* rhB   = (unsigned short*)(wsb);                   // Gn*64*2 = 2,048,000
    unsigned short* vBg   = (unsigned short*)(wsb + 2048000);         // Bn*64*2 =   524,288
    float*          v64   = (float*)(wsb + 2572288);                  // Bn*4    =    16,384
    float*          lsp1c = (float*)(wsb + 2588672);                  // Gn*4
    float*          lsn2  = (float*)(wsb + 2652672);                  // Gn*4
    float*          eps   = (float*)(wsb + 2716672);                  // Gn*4

    // zero loss accumulators AND the two scalar slots
    hipMemsetAsync(d_out, 0, (Bn + 2) * sizeof(float), stream);

    prep_genes<<<(Gn * 64) / 256, 256, 0, stream>>>(W, px_o, eta, beta, rhB, lsp1c, lsn2, eps);
    prep_spots<<<(Bn * 64) / 256, 256, 0, stream>>>(V, ind_x, vBg, v64);
    prior_kernel<<<(Gn + 255) / 256, 256, 0, stream>>>(eta, out);

    dim3 grid(Gn / 64, Bn / 128);   // 250 x 32, two 64-row tiles per block
    main_kernel<<<grid, 256, 0, stream>>>(x, rhB, vBg, v64, lsp1c, lsn2, eps, out);
}